// Round 16
// baseline (122.931 us; speedup 1.0000x reference)
//
#include <hip/hip_runtime.h>
#include <math.h>

typedef _Float16 half_t;
typedef half_t half8 __attribute__((ext_vector_type(8)));
typedef __fp16 fp16x2 __attribute__((ext_vector_type(2)));   // cvt_pkrtz return type
typedef float f32x4 __attribute__((ext_vector_type(4)));
typedef float f32x2 __attribute__((ext_vector_type(2)));     // -> v_pk_*_f32

#define PI_F 3.14159265358979323846f

__device__ __forceinline__ f32x2 splat2(float s) { return f32x2{s, s}; }
__device__ __forceinline__ f32x2 fma2(f32x2 a, f32x2 b, f32x2 c) {
    return __builtin_elementwise_fma(a, b, c);
}

// Fast tanh (packed pair): tanh(z) = 1 - 2*rcp(e^{2z}+1), e^{2z} = 2^(z*2/ln2).
// 7 wave-ops/pair. No clamp (|z| < ~10 here; overflow needs |z| > 44).
__device__ __forceinline__ f32x2 ftanh2(f32x2 z) {
    const f32x2 m = z * splat2(2.8853900817779268f);   // 2/ln2
    f32x2 t;
    t[0] = exp2f(m[0]);          // v_exp_f32
    t[1] = exp2f(m[1]);
    const f32x2 s = t + splat2(1.f);
    f32x2 r;
    r[0] = __builtin_amdgcn_rcpf(s[0]);
    r[1] = __builtin_amdgcn_rcpf(s[1]);
    return fma2(splat2(-2.f), r, splat2(1.f));
}

// DIRECTIONAL-JET (R15): interior {v, x, d, dd}, d = dx+dt; boundary
// {v,x,t,xt,tt,xtt}. Residual = 4*pi*cos - 2*pi^2*x*s + 2(A+B+A'B')D
// + 2(AB'+A'B)Dd + AB*Ddd + psi*psi_x - forcing (exact rearrangement).
//
// FUSED GEMV (R16): L3 compose keeps h3 in registers; u_c partial =
// f32 dot with Wo over the thread's 4 neurons; shfl_xor(16,32) sums the
// wave; ubuf[4][7][16] stages cross-wave. Removes L3 J-writes, the GEMV
// MFMA phase, wo f16 frags (-8 VGPR), and 2 of 6 barriers per pass.
//
// TRANSPOSED layout: J^T[n = c*16 + p][k = j], XOR-swizzled:
//   halfidx(n,k) = n*64 + (((k>>3) ^ (n&7)) << 3) + (k&7)
// OCCUPANCY CLIFF (R11+R13): stay VGPR<=84 (73 for the next step), LDS
// small, no hoisting, no double-buffer, no launch_bounds occupancy arg (R4).
__global__ __launch_bounds__(256) void pinn_main(
    const float* __restrict__ pts,
    const float* __restrict__ W1, const float* __restrict__ b1,
    const float* __restrict__ b2, const float* __restrict__ b3,
    const float* __restrict__ Wo,
    const half_t* __restrict__ wsH,    // Wt2 @0, Wt3 @4096 (half idx)
    float* __restrict__ partial)
{
    __shared__ __align__(16) half_t J[160 * 64];   // 20 KB
    __shared__ float ubuf[4][7][16];               // per-wave partial u stage

    const int tid = threadIdx.x;
    const int l   = tid & 63;
    const int w   = tid >> 6;       // wave = output-neuron M-tile (rows of Z^T)
    const int q   = l >> 4;
    const int i   = l & 15;         // = point p owned for compose/writes
    const int ja  = w * 16 + i;     // A-operand weight row
    const int jb  = w * 16 + q * 4; // first of 4 output-neuron cols owned

    // loop-invariant LDS bases (halves)
    const int rb0 = i * 64 + ((q ^ (i & 7)) << 3);          // B-frag, k-chunk q*8
    const int rb1 = i * 64 + (((4 + q) ^ (i & 7)) << 3);    // B-frag, k-chunk 32+q*8
    const int wbase = i * 64 + ((((w * 2 + (q >> 1)) ^ (i & 7))) << 3) + (q & 1) * 4;

    // A-operand fragments (weights, registers — pass-invariant)
    const half8 w2a = *(const half8*)(wsH + ja * 64 + q * 8);
    const half8 w2b = *(const half8*)(wsH + ja * 64 + 32 + q * 8);
    const half8 w3a = *(const half8*)(wsH + 4096 + ja * 64 + q * 8);
    const half8 w3b = *(const half8*)(wsH + 4096 + ja * 64 + 32 + q * 8);

    // per-output-neuron params: 4 contiguous -> float4 loads
    const float4 w04 = *(const float4*)(W1 + jb);
    const float4 w14 = *(const float4*)(W1 + 64 + jb);
    const float4 b14 = *(const float4*)(b1 + jb);
    const float4 b24 = *(const float4*)(b2 + jb);
    const float4 b34 = *(const float4*)(b3 + jb);
    const float4 wo4 = *(const float4*)(Wo + jb);   // f32 GEMV weights

    // packed write: one b64 = comp c for 4 neurons; pure bit-cast (no v-inserts)
    auto stc = [&](int c, f32x2 v01, f32x2 v23) {
        uint2 d;
        d.x = __builtin_bit_cast(unsigned int,
                                 __builtin_amdgcn_cvt_pkrtz(v01[0], v01[1]));
        d.y = __builtin_bit_cast(unsigned int,
                                 __builtin_amdgcn_cvt_pkrtz(v23[0], v23[1]));
        *(uint2*)(&J[wbase + c * 1024]) = d;
    };

    // neuron-pair packed layer-1 params (no derived-product hoisting — R11)
    const f32x2 w0a = {w04.x, w04.y}, w0b = {w04.z, w04.w};
    const f32x2 w1a = {w14.x, w14.y}, w1b = {w14.z, w14.w};
    const f32x2 bba = {b14.x, b14.y}, bbb = {b14.z, b14.w};
    const f32x2 woA = {wo4.x, wo4.y}, woB = {wo4.z, wo4.w};

    // per-thread Wo-dot over 4 owned neurons (pairs 01, 23)
    auto dot4 = [&](f32x2 v01, f32x2 v23) -> float {
        f32x2 t = v01 * woA;
        t = fma2(v23, woB, t);
        return t[0] + t[1];
    };

    float bsum = 0.f;

    #pragma unroll 1
    for (int pass = 0; pass < 2; ++pass) {
        const int pbase = blockIdx.x * 32 + pass * 16;

        const float2 xy = *(const float2*)(pts + 2 * (pbase + i));   // point p = i
        const float X = xy.x, T = xy.y;

        // -------- layer 1 (2 -> 64): jets for point i, 4 neurons --------
        {   // interior jet at (x,t): {v, x, d, dd}; z_x=w0, z_d=w0+w1, z_dd=0
            const f32x2 wda = w0a + w1a, wdb = w0b + w1b;
            const f32x2 zva = fma2(splat2(X), w0a, fma2(splat2(T), w1a, bba));
            const f32x2 zvb = fma2(splat2(X), w0b, fma2(splat2(T), w1b, bbb));
            const f32x2 aa = ftanh2(zva), ab = ftanh2(zvb);
            const f32x2 d1a = splat2(1.f) - aa * aa, d1b = splat2(1.f) - ab * ab;
            const f32x2 d2a = splat2(-2.f) * aa * d1a, d2b = splat2(-2.f) * ab * d1b;
            stc(0, aa, ab);
            stc(1, d1a * w0a, d1b * w0b);
            stc(2, d1a * wda, d1b * wdb);
            stc(3, d2a * wda * wda, d2b * wdb * wdb);
        }
        {   // boundary jet at (1,t): {v, x, t, xt, tt, xtt} (comps 4..9)
            const f32x2 zva = fma2(splat2(T), w1a, bba + w0a);
            const f32x2 zvb = fma2(splat2(T), w1b, bbb + w0b);
            const f32x2 aa = ftanh2(zva), ab = ftanh2(zvb);
            const f32x2 e1a = splat2(1.f) - aa * aa, e1b = splat2(1.f) - ab * ab;
            const f32x2 e2a = splat2(-2.f) * aa * e1a, e2b = splat2(-2.f) * ab * e1b;
            const f32x2 e3a = splat2(-2.f) * (e1a * e1a + aa * e2a);
            const f32x2 e3b = splat2(-2.f) * (e1b * e1b + ab * e2b);
            stc(4, aa, ab);
            stc(5, e1a * w0a, e1b * w0b);
            stc(6, e1a * w1a, e1b * w1b);
            stc(7, e2a * w0a * w1a, e2b * w0b * w1b);
            stc(8, e2a * w1a * w1a, e2b * w1b * w1b);
            stc(9, e3a * w0a * w1a * w1a, e3b * w0b * w1b * w1b);
        }

        // -------- L2: MFMA jet-GEMM + packed compose, J in-place --------
        {
            __syncthreads();   // bar1: J1 ready
            const f32x4 zb = {b24.x, b24.y, b24.z, b24.w};
            const f32x4 z0 = {0.f, 0.f, 0.f, 0.f};
            f32x4 acc[10];
            #pragma unroll
            for (int c = 0; c < 10; ++c) {
                const half8 f0 = *(const half8*)(&J[rb0 + c * 1024]);
                const half8 f1 = *(const half8*)(&J[rb1 + c * 1024]);
                f32x4 z = (c == 0 || c == 4) ? zb : z0;   // bias into C-init (v comps)
                z = __builtin_amdgcn_mfma_f32_16x16x32_f16(w2a, f0, z, 0, 0, 0);
                z = __builtin_amdgcn_mfma_f32_16x16x32_f16(w2b, f1, z, 0, 0, 0);
                acc[c] = z;
            }
            __syncthreads();   // bar2: all reads of J done

            {   // interior jet {v, x, d, dd}, neuron pairs (01),(23)
                const f32x2 zva = {acc[0][0], acc[0][1]}, zvb = {acc[0][2], acc[0][3]};
                const f32x2 aa = ftanh2(zva), ab = ftanh2(zvb);
                const f32x2 d1a = splat2(1.f) - aa * aa, d1b = splat2(1.f) - ab * ab;
                const f32x2 d2a = splat2(-2.f) * aa * d1a, d2b = splat2(-2.f) * ab * d1b;
                const f32x2 zxa = {acc[1][0], acc[1][1]}, zxb = {acc[1][2], acc[1][3]};
                const f32x2 zda = {acc[2][0], acc[2][1]}, zdb = {acc[2][2], acc[2][3]};
                const f32x2 zdda = {acc[3][0], acc[3][1]}, zddb = {acc[3][2], acc[3][3]};
                stc(0, aa, ab);
                stc(1, d1a * zxa, d1b * zxb);
                stc(2, d1a * zda, d1b * zdb);
                stc(3, fma2(d2a * zda, zda, d1a * zdda),
                       fma2(d2b * zdb, zdb, d1b * zddb));
            }
            {   // boundary jet (comps 4..9)
                const f32x2 zva = {acc[4][0], acc[4][1]}, zvb = {acc[4][2], acc[4][3]};
                const f32x2 aa = ftanh2(zva), ab = ftanh2(zvb);
                const f32x2 e1a = splat2(1.f) - aa * aa, e1b = splat2(1.f) - ab * ab;
                const f32x2 e2a = splat2(-2.f) * aa * e1a, e2b = splat2(-2.f) * ab * e1b;
                const f32x2 e3a = splat2(-2.f) * (e1a * e1a + aa * e2a);
                const f32x2 e3b = splat2(-2.f) * (e1b * e1b + ab * e2b);
                const f32x2 zxa  = {acc[5][0], acc[5][1]},  zxb  = {acc[5][2], acc[5][3]};
                const f32x2 zta  = {acc[6][0], acc[6][1]},  ztb  = {acc[6][2], acc[6][3]};
                const f32x2 zxta = {acc[7][0], acc[7][1]},  zxtb = {acc[7][2], acc[7][3]};
                const f32x2 ztta = {acc[8][0], acc[8][1]},  zttb = {acc[8][2], acc[8][3]};
                const f32x2 zxtta = {acc[9][0], acc[9][1]}, zxttb = {acc[9][2], acc[9][3]};
                stc(4, aa, ab);
                stc(5, e1a * zxa, e1b * zxb);
                stc(6, e1a * zta, e1b * ztb);
                stc(7, fma2(e2a * zxa, zta, e1a * zxta),
                       fma2(e2b * zxb, ztb, e1b * zxtb));
                stc(8, fma2(e2a * zta, zta, e1a * ztta),
                        fma2(e2b * ztb, ztb, e1b * zttb));
                stc(9,
                    fma2(e3a * zxa, zta * zta,
                         fma2(e2a, fma2(splat2(2.f) * zxta, zta, zxa * ztta),
                              e1a * zxtta)),
                    fma2(e3b * zxb, ztb * ztb,
                         fma2(e2b, fma2(splat2(2.f) * zxtb, ztb, zxb * zttb),
                              e1b * zxttb)));
            }
        }

        // -------- L3: GEMM + compose in regs + fused Wo-dot (no J writes) --------
        {
            __syncthreads();   // bar3: J2 ready
            const f32x4 zb = {b34.x, b34.y, b34.z, b34.w};
            const f32x4 z0 = {0.f, 0.f, 0.f, 0.f};
            f32x4 acc[10];
            #pragma unroll
            for (int c = 0; c < 10; ++c) {
                const half8 f0 = *(const half8*)(&J[rb0 + c * 1024]);
                const half8 f1 = *(const half8*)(&J[rb1 + c * 1024]);
                f32x4 z = (c == 0 || c == 4) ? zb : z0;
                z = __builtin_amdgcn_mfma_f32_16x16x32_f16(w3a, f0, z, 0, 0, 0);
                z = __builtin_amdgcn_mfma_f32_16x16x32_f16(w3b, f1, z, 0, 0, 0);
                acc[c] = z;
            }
            // no barrier: J is not written again until next-pass L1, which is
            // guarded by bar4 below (also covers these reads).

            float s[7];
            {   // interior jet {v, x, d, dd}
                const f32x2 zva = {acc[0][0], acc[0][1]}, zvb = {acc[0][2], acc[0][3]};
                const f32x2 aa = ftanh2(zva), ab = ftanh2(zvb);
                const f32x2 d1a = splat2(1.f) - aa * aa, d1b = splat2(1.f) - ab * ab;
                const f32x2 d2a = splat2(-2.f) * aa * d1a, d2b = splat2(-2.f) * ab * d1b;
                const f32x2 zxa = {acc[1][0], acc[1][1]}, zxb = {acc[1][2], acc[1][3]};
                const f32x2 zda = {acc[2][0], acc[2][1]}, zdb = {acc[2][2], acc[2][3]};
                const f32x2 zdda = {acc[3][0], acc[3][1]}, zddb = {acc[3][2], acc[3][3]};
                s[0] = dot4(aa, ab);
                s[1] = dot4(d1a * zxa, d1b * zxb);
                s[2] = dot4(d1a * zda, d1b * zdb);
                s[3] = dot4(fma2(d2a * zda, zda, d1a * zdda),
                            fma2(d2b * zdb, zdb, d1b * zddb));
            }
            {   // boundary jet, combined: B0=v+x, B1=t+xt, B2=tt+xtt (exact)
                const f32x2 zva = {acc[4][0], acc[4][1]}, zvb = {acc[4][2], acc[4][3]};
                const f32x2 aa = ftanh2(zva), ab = ftanh2(zvb);
                const f32x2 e1a = splat2(1.f) - aa * aa, e1b = splat2(1.f) - ab * ab;
                const f32x2 e2a = splat2(-2.f) * aa * e1a, e2b = splat2(-2.f) * ab * e1b;
                const f32x2 e3a = splat2(-2.f) * (e1a * e1a + aa * e2a);
                const f32x2 e3b = splat2(-2.f) * (e1b * e1b + ab * e2b);
                const f32x2 zxa  = {acc[5][0], acc[5][1]},  zxb  = {acc[5][2], acc[5][3]};
                const f32x2 zta  = {acc[6][0], acc[6][1]},  ztb  = {acc[6][2], acc[6][3]};
                const f32x2 zxta = {acc[7][0], acc[7][1]},  zxtb = {acc[7][2], acc[7][3]};
                const f32x2 ztta = {acc[8][0], acc[8][1]},  zttb = {acc[8][2], acc[8][3]};
                const f32x2 zxtta = {acc[9][0], acc[9][1]}, zxttb = {acc[9][2], acc[9][3]};
                s[4] = dot4(aa + e1a * zxa, ab + e1b * zxb);
                s[5] = dot4(fma2(e2a * zxa, zta, fma2(e1a, zxta, e1a * zta)),
                            fma2(e2b * zxb, ztb, fma2(e1b, zxtb, e1b * ztb)));
                s[6] = dot4(fma2(e2a * zta, zta,
                                 fma2(e1a, ztta,
                                      fma2(e3a * zxa, zta * zta,
                                           fma2(e2a, fma2(splat2(2.f) * zxta, zta,
                                                          zxa * ztta),
                                                e1a * zxtta)))),
                            fma2(e2b * ztb, ztb,
                                 fma2(e1b, zttb,
                                      fma2(e3b * zxb, ztb * ztb,
                                           fma2(e2b, fma2(splat2(2.f) * zxtb, ztb,
                                                          zxb * zttb),
                                                e1b * zxttb)))));
            }
            #pragma unroll
            for (int c = 0; c < 7; ++c) {   // sum the 4 q-groups of this wave
                s[c] += __shfl_xor(s[c], 16, 64);
                s[c] += __shfl_xor(s[c], 32, 64);
            }
            if (l < 16) {
                #pragma unroll
                for (int c = 0; c < 7; ++c) ubuf[w][c][l] = s[c];
            }
        }
        __syncthreads();   // bar4: ubuf ready + all J reads done (next L1 safe)

        // ---------------- residual: one lane per point ----------------
        if (tid < 16) {
            // for tid<16: w=0,q=0,i=tid -> X,T are this point's coords
            const float x = X, t = T;
            float U[7];
            #pragma unroll
            for (int c = 0; c < 7; ++c)
                U[c] = (ubuf[0][c][tid] + ubuf[1][c][tid])
                     + (ubuf[2][c][tid] + ubuf[3][c][tid]);

            const float D   = U[0] - U[4];     // u - (uB + uBx)
            const float Dx  = U[1];
            const float Dd  = U[2] - U[5];     // u_d - (uBt + uBxt)
            const float Ddd = U[3] - U[6];     // u_dd - (uBtt + uBxtt)

            // sin(pi t) = v_sin(t/2) [revolutions], t in [0,1]
            const float s  = __builtin_amdgcn_sinf(0.5f * t);
            const float cc = __builtin_amdgcn_cosf(0.5f * t);
            const float A  = t * t - t,  Ap = 2.f * t - 1.f;
            const float B  = x * x - x,  Bp = 2.f * x - 1.f;

            const float psi   = 2.f * x * s + A * B * D;
            const float psi_x = 2.f * s + A * (Bp * D + B * Dx);

            const float forcing = s * (2.f - PI_F * PI_F * x * x
                                       + 2.f * x * x * x * s);
            const float res = 4.f * PI_F * cc - 2.f * PI_F * PI_F * x * s
                            + 2.f * (A + B + Ap * Bp) * D
                            + 2.f * (A * Bp + Ap * B) * Dd
                            + A * B * Ddd
                            + psi * psi_x - forcing;
            float s4 = fabsf(res);
            s4 += __shfl_xor(s4, 1, 64);
            s4 += __shfl_xor(s4, 2, 64);
            s4 += __shfl_xor(s4, 4, 64);
            s4 += __shfl_xor(s4, 8, 64);
            if (tid == 0) bsum += s4;
        }
    }

    if (tid == 0) partial[blockIdx.x] = bsum;
}

__global__ __launch_bounds__(256) void pinn_prep(
    const float* __restrict__ W2, const float* __restrict__ W3,
    half_t* __restrict__ wsH)
{
    const int tid = threadIdx.x;
    for (int idx = tid; idx < 4096; idx += 256) {
        const int n = idx >> 6, k = idx & 63;
        wsH[idx]        = (half_t)W2[k * 64 + n];   // Wt2[n][k]
        wsH[4096 + idx] = (half_t)W3[k * 64 + n];   // Wt3[n][k]
    }
}

__global__ __launch_bounds__(256) void pinn_reduce(
    const float* __restrict__ partial, float* __restrict__ out,
    int nblocks, float invN)
{
    __shared__ float sd[256];
    float s = 0.f;
    for (int i = threadIdx.x; i < nblocks; i += 256) s += partial[i];
    sd[threadIdx.x] = s;
    __syncthreads();
    #pragma unroll
    for (int off = 128; off > 0; off >>= 1) {
        if (threadIdx.x < off) sd[threadIdx.x] += sd[threadIdx.x + off];
        __syncthreads();
    }
    if (threadIdx.x == 0) out[0] = sd[0] * invN;
}

extern "C" void kernel_launch(void* const* d_in, const int* in_sizes, int n_in,
                              void* d_out, int out_size, void* d_ws, size_t ws_size,
                              hipStream_t stream)
{
    const float* pts = (const float*)d_in[0];
    const float* W1  = (const float*)d_in[1];
    const float* b1  = (const float*)d_in[2];
    const float* W2  = (const float*)d_in[3];
    const float* b2  = (const float*)d_in[4];
    const float* W3  = (const float*)d_in[5];
    const float* b3  = (const float*)d_in[6];
    const float* Wo  = (const float*)d_in[7];
    // d_in[8] = bo: cancels in (u - u(1,t)) and has zero derivative.

    const int nPts    = in_sizes[0] / 2;          // 262144
    const int nBlocks = nPts / 32;                // 8192 (32 pts = 2 passes x 16)

    half_t* wsH     = (half_t*)d_ws;                      // 16,384 B of weights
    float*  partial = (float*)((char*)d_ws + 32768);      // 32 KB of partials

    pinn_prep<<<1, 256, 0, stream>>>(W2, W3, wsH);
    pinn_main<<<nBlocks, 256, 0, stream>>>(pts, W1, b1, b2, b3, Wo, wsH, partial);
    pinn_reduce<<<1, 256, 0, stream>>>(partial, (float*)d_out, nBlocks,
                                       1.f / (float)nPts);
}

// Round 17
// 116.885 us; speedup vs baseline: 1.0517x; 1.0517x over previous
//
#include <hip/hip_runtime.h>
#include <math.h>

typedef _Float16 half_t;
typedef half_t half8 __attribute__((ext_vector_type(8)));
typedef __fp16 fp16x2 __attribute__((ext_vector_type(2)));   // cvt_pkrtz return type
typedef float f32x4 __attribute__((ext_vector_type(4)));
typedef float f32x2 __attribute__((ext_vector_type(2)));     // -> v_pk_*_f32

#define PI_F 3.14159265358979323846f

__device__ __forceinline__ f32x2 splat2(float s) { return f32x2{s, s}; }
__device__ __forceinline__ f32x2 fma2(f32x2 a, f32x2 b, f32x2 c) {
    return __builtin_elementwise_fma(a, b, c);
}

// Fast tanh (packed pair): tanh(z) = 1 - 2*rcp(e^{2z}+1), e^{2z} = 2^(z*2/ln2).
// 7 wave-ops/pair. No clamp (|z| < ~10 here; overflow needs |z| > 44).
__device__ __forceinline__ f32x2 ftanh2(f32x2 z) {
    const f32x2 m = z * splat2(2.8853900817779268f);   // 2/ln2
    f32x2 t;
    t[0] = exp2f(m[0]);          // v_exp_f32
    t[1] = exp2f(m[1]);
    const f32x2 s = t + splat2(1.f);
    f32x2 r;
    r[0] = __builtin_amdgcn_rcpf(s[0]);
    r[1] = __builtin_amdgcn_rcpf(s[1]);
    return fma2(splat2(-2.f), r, splat2(1.f));
}

// ===== R17 = exact revert to R15 (measured optimum 116.8us) =====
//
// DIRECTIONAL-JET (R15): the residual uses only
//   psi_xx + 2 psi_xt + psi_tt = (d/d(1,1))^2 psi,
// so the interior point needs just {u, u_x, u_d, u_dd}, d = dx+dt.
// Residual (exact rearrangement): res = 4*pi*cos - 2*pi^2*x*s
//   + 2(A+B+A'B')D + 2(AB'+A'B)Dd + AB*Ddd + psi*psi_x - forcing.
// Comp map: 0..3 interior {v,x,d,dd}; 4..9 boundary {v,x,t,xt,tt,xtt};
// L3 combines boundary to 3 (B0=v+x, B1=t+xt, B2=tt+xtt; GEMV linear, exact).
//
// TRANSPOSED layout: J^T[n = c*16 + p][k = j], XOR-swizzled:
//   halfidx(n,k) = n*64 + (((k>>3) ^ (n&7)) << 3) + (k&7)
//
// LESSONS (do not revisit):
//  R4:  launch_bounds occupancy arg -> acc spill, 2.2GB scratch, 2x slower.
//  R11: hoisting pass-invariant products -> VGPR 88, -1 wave/EU, +21%.
//  R13: LDS ping-pong dbuf -> 50KB LDS + VGPR 92, -30% occupancy, +15%.
//  R16: fusing GEMV out of MFMA into shfl/VALU -> moved work from the 17%-
//       utilized MFMA pipe onto the 64%-busy VALU/DS path, +5%. Keep the
//       GEMV on MFMA: fuse INTO the idle pipe, never out of it.
// OCCUPANCY CLIFF: stay VGPR<=84, LDS small, 6 barriers/pass is optimal.
__global__ __launch_bounds__(256) void pinn_main(
    const float* __restrict__ pts,
    const float* __restrict__ W1, const float* __restrict__ b1,
    const float* __restrict__ b2, const float* __restrict__ b3,
    const half_t* __restrict__ wsH,    // Wt2 @0, Wt3 @4096, Wo @8192 (half idx)
    float* __restrict__ partial)
{
    __shared__ __align__(16) half_t J[160 * 64];   // 20 KB
    __shared__ float ubuf[7][16];                  // u[c][p] stage for residual

    const int tid = threadIdx.x;
    const int l   = tid & 63;
    const int w   = tid >> 6;       // wave = output-neuron M-tile (rows of Z^T)
    const int q   = l >> 4;
    const int i   = l & 15;         // = point p owned for compose/writes
    const int ja  = w * 16 + i;     // A-operand weight row
    const int jb  = w * 16 + q * 4; // first of 4 output-neuron cols owned

    // loop-invariant LDS bases (halves)
    const int rb0 = i * 64 + ((q ^ (i & 7)) << 3);          // B-frag, k-chunk q*8
    const int rb1 = i * 64 + (((4 + q) ^ (i & 7)) << 3);    // B-frag, k-chunk 32+q*8
    const int wbase = i * 64 + ((((w * 2 + (q >> 1)) ^ (i & 7))) << 3) + (q & 1) * 4;

    // A-operand fragments (weights, registers — pass-invariant)
    const half8 w2a = *(const half8*)(wsH + ja * 64 + q * 8);
    const half8 w2b = *(const half8*)(wsH + ja * 64 + 32 + q * 8);
    const half8 w3a = *(const half8*)(wsH + 4096 + ja * 64 + q * 8);
    const half8 w3b = *(const half8*)(wsH + 4096 + ja * 64 + 32 + q * 8);

    // per-output-neuron params: 4 contiguous -> float4 loads
    const float4 w04 = *(const float4*)(W1 + jb);
    const float4 w14 = *(const float4*)(W1 + 64 + jb);
    const float4 b14 = *(const float4*)(b1 + jb);
    const float4 b24 = *(const float4*)(b2 + jb);
    const float4 b34 = *(const float4*)(b3 + jb);

    half8 wo0 = {0, 0, 0, 0, 0, 0, 0, 0};   // GEMV A-frag: row 0 = Wo
    half8 wo1 = {0, 0, 0, 0, 0, 0, 0, 0};
    if (i == 0) {
        wo0 = *(const half8*)(wsH + 8192 + q * 8);
        wo1 = *(const half8*)(wsH + 8192 + 32 + q * 8);
    }

    // packed write: one b64 = comp c for 4 neurons; pure bit-cast (no v-inserts)
    auto stc = [&](int c, f32x2 v01, f32x2 v23) {
        uint2 d;
        d.x = __builtin_bit_cast(unsigned int,
                                 __builtin_amdgcn_cvt_pkrtz(v01[0], v01[1]));
        d.y = __builtin_bit_cast(unsigned int,
                                 __builtin_amdgcn_cvt_pkrtz(v23[0], v23[1]));
        *(uint2*)(&J[wbase + c * 1024]) = d;
    };

    // neuron-pair packed layer-1 params (no derived-product hoisting — R11)
    const f32x2 w0a = {w04.x, w04.y}, w0b = {w04.z, w04.w};
    const f32x2 w1a = {w14.x, w14.y}, w1b = {w14.z, w14.w};
    const f32x2 bba = {b14.x, b14.y}, bbb = {b14.z, b14.w};

    float bsum = 0.f;

    #pragma unroll 1
    for (int pass = 0; pass < 2; ++pass) {
        const int pbase = blockIdx.x * 32 + pass * 16;

        const float2 xy = *(const float2*)(pts + 2 * (pbase + i));   // point p = i
        const float X = xy.x, T = xy.y;

        // -------- layer 1 (2 -> 64): jets for point i, 4 neurons --------
        {   // interior jet at (x,t): {v, x, d, dd}; z_x=w0, z_d=w0+w1, z_dd=0
            const f32x2 wda = w0a + w1a, wdb = w0b + w1b;
            const f32x2 zva = fma2(splat2(X), w0a, fma2(splat2(T), w1a, bba));
            const f32x2 zvb = fma2(splat2(X), w0b, fma2(splat2(T), w1b, bbb));
            const f32x2 aa = ftanh2(zva), ab = ftanh2(zvb);
            const f32x2 d1a = splat2(1.f) - aa * aa, d1b = splat2(1.f) - ab * ab;
            const f32x2 d2a = splat2(-2.f) * aa * d1a, d2b = splat2(-2.f) * ab * d1b;
            stc(0, aa, ab);
            stc(1, d1a * w0a, d1b * w0b);
            stc(2, d1a * wda, d1b * wdb);
            stc(3, d2a * wda * wda, d2b * wdb * wdb);
        }
        {   // boundary jet at (1,t): {v, x, t, xt, tt, xtt} (comps 4..9)
            const f32x2 zva = fma2(splat2(T), w1a, bba + w0a);
            const f32x2 zvb = fma2(splat2(T), w1b, bbb + w0b);
            const f32x2 aa = ftanh2(zva), ab = ftanh2(zvb);
            const f32x2 e1a = splat2(1.f) - aa * aa, e1b = splat2(1.f) - ab * ab;
            const f32x2 e2a = splat2(-2.f) * aa * e1a, e2b = splat2(-2.f) * ab * e1b;
            const f32x2 e3a = splat2(-2.f) * (e1a * e1a + aa * e2a);
            const f32x2 e3b = splat2(-2.f) * (e1b * e1b + ab * e2b);
            stc(4, aa, ab);
            stc(5, e1a * w0a, e1b * w0b);
            stc(6, e1a * w1a, e1b * w1b);
            stc(7, e2a * w0a * w1a, e2b * w0b * w1b);
            stc(8, e2a * w1a * w1a, e2b * w1b * w1b);
            stc(9, e3a * w0a * w1a * w1a, e3b * w0b * w1b * w1b);
        }

        // -------- hidden layer: MFMA jet-GEMM + packed compose --------
        auto layer_step = [&](const half8 A0, const half8 A1, const float4 b4,
                              bool combine) {
            __syncthreads();   // J ready
            const f32x4 zb = {b4.x, b4.y, b4.z, b4.w};
            const f32x4 z0 = {0.f, 0.f, 0.f, 0.f};
            f32x4 acc[10];
            #pragma unroll
            for (int c = 0; c < 10; ++c) {
                const half8 f0 = *(const half8*)(&J[rb0 + c * 1024]);
                const half8 f1 = *(const half8*)(&J[rb1 + c * 1024]);
                f32x4 z = (c == 0 || c == 4) ? zb : z0;   // bias into C-init (v comps)
                z = __builtin_amdgcn_mfma_f32_16x16x32_f16(A0, f0, z, 0, 0, 0);
                z = __builtin_amdgcn_mfma_f32_16x16x32_f16(A1, f1, z, 0, 0, 0);
                acc[c] = z;
            }
            __syncthreads();   // all reads of J done

            {   // interior jet {v, x, d, dd}, neuron pairs (01),(23)
                const f32x2 zva = {acc[0][0], acc[0][1]}, zvb = {acc[0][2], acc[0][3]};
                const f32x2 aa = ftanh2(zva), ab = ftanh2(zvb);
                const f32x2 d1a = splat2(1.f) - aa * aa, d1b = splat2(1.f) - ab * ab;
                const f32x2 d2a = splat2(-2.f) * aa * d1a, d2b = splat2(-2.f) * ab * d1b;
                const f32x2 zxa = {acc[1][0], acc[1][1]}, zxb = {acc[1][2], acc[1][3]};
                const f32x2 zda = {acc[2][0], acc[2][1]}, zdb = {acc[2][2], acc[2][3]};
                const f32x2 zdda = {acc[3][0], acc[3][1]}, zddb = {acc[3][2], acc[3][3]};
                stc(0, aa, ab);
                stc(1, d1a * zxa, d1b * zxb);
                stc(2, d1a * zda, d1b * zdb);
                stc(3, fma2(d2a * zda, zda, d1a * zdda),
                       fma2(d2b * zdb, zdb, d1b * zddb));
            }
            {   // boundary jet (comps 4..9)
                const f32x2 zva = {acc[4][0], acc[4][1]}, zvb = {acc[4][2], acc[4][3]};
                const f32x2 aa = ftanh2(zva), ab = ftanh2(zvb);
                const f32x2 e1a = splat2(1.f) - aa * aa, e1b = splat2(1.f) - ab * ab;
                const f32x2 e2a = splat2(-2.f) * aa * e1a, e2b = splat2(-2.f) * ab * e1b;
                const f32x2 e3a = splat2(-2.f) * (e1a * e1a + aa * e2a);
                const f32x2 e3b = splat2(-2.f) * (e1b * e1b + ab * e2b);
                const f32x2 zxa  = {acc[5][0], acc[5][1]},  zxb  = {acc[5][2], acc[5][3]};
                const f32x2 zta  = {acc[6][0], acc[6][1]},  ztb  = {acc[6][2], acc[6][3]};
                const f32x2 zxta = {acc[7][0], acc[7][1]},  zxtb = {acc[7][2], acc[7][3]};
                const f32x2 ztta = {acc[8][0], acc[8][1]},  zttb = {acc[8][2], acc[8][3]};
                const f32x2 zxtta = {acc[9][0], acc[9][1]}, zxttb = {acc[9][2], acc[9][3]};
                if (combine) {   // residual uses only (v+x), (t+xt), (tt+xtt) — exact
                    stc(4, aa + e1a * zxa, ab + e1b * zxb);
                    stc(5, fma2(e2a * zxa, zta, fma2(e1a, zxta, e1a * zta)),
                           fma2(e2b * zxb, ztb, fma2(e1b, zxtb, e1b * ztb)));
                    stc(6, fma2(e2a * zta, zta,
                                fma2(e1a, ztta,
                                     fma2(e3a * zxa, zta * zta,
                                          fma2(e2a, fma2(splat2(2.f) * zxta, zta,
                                                         zxa * ztta),
                                               e1a * zxtta)))),
                           fma2(e2b * ztb, ztb,
                                fma2(e1b, zttb,
                                     fma2(e3b * zxb, ztb * ztb,
                                          fma2(e2b, fma2(splat2(2.f) * zxtb, ztb,
                                                         zxb * zttb),
                                               e1b * zxttb)))));
                } else {
                    stc(4, aa, ab);
                    stc(5, e1a * zxa, e1b * zxb);
                    stc(6, e1a * zta, e1b * ztb);
                    stc(7, fma2(e2a * zxa, zta, e1a * zxta),
                           fma2(e2b * zxb, ztb, e1b * zxtb));
                    stc(8, fma2(e2a * zta, zta, e1a * ztta),
                            fma2(e2b * ztb, ztb, e1b * zttb));
                    stc(9,
                        fma2(e3a * zxa, zta * zta,
                             fma2(e2a, fma2(splat2(2.f) * zxta, zta, zxa * ztta),
                                  e1a * zxtta)),
                        fma2(e3b * zxb, ztb * ztb,
                             fma2(e2b, fma2(splat2(2.f) * zxtb, ztb, zxb * zttb),
                                  e1b * zxttb)));
                }
            }
        };
        layer_step(w2a, w2b, b24, false);
        layer_step(w3a, w3b, b34, true);    // 7-comp J3
        __syncthreads();   // J3 ready

        // ---- output GEMV (Wo as A row 0): 7 tiles, wave w owns c = 2w, 2w+1 ----
        {
            #pragma unroll
            for (int k3 = 0; k3 < 2; ++k3) {
                const int c = w * 2 + k3;
                if (c < 7) {
                    const half8 f0 = *(const half8*)(&J[rb0 + c * 1024]);
                    const half8 f1 = *(const half8*)(&J[rb1 + c * 1024]);
                    f32x4 z = {0.f, 0.f, 0.f, 0.f};
                    z = __builtin_amdgcn_mfma_f32_16x16x32_f16(wo0, f0, z, 0, 0, 0);
                    z = __builtin_amdgcn_mfma_f32_16x16x32_f16(wo1, f1, z, 0, 0, 0);
                    if (q == 0) ubuf[c][i] = z[0];   // D row 0 -> q==0 lanes, reg 0
                }
            }
        }
        __syncthreads();   // ubuf ready; all J reads done (next L1 may write J)

        // ---------------- residual: one lane per point ----------------
        if (tid < 16) {
            // for tid<16: w=0,q=0,i=tid -> X,T are this point's coords
            const float x = X, t = T;
            float U[7];
            #pragma unroll
            for (int c = 0; c < 7; ++c) U[c] = ubuf[c][tid];

            const float D   = U[0] - U[4];     // u - (uB + uBx)
            const float Dx  = U[1];
            const float Dd  = U[2] - U[5];     // u_d - (uBt + uBxt)
            const float Ddd = U[3] - U[6];     // u_dd - (uBtt + uBxtt)

            // sin(pi t) = v_sin(t/2) [revolutions], t in [0,1]
            const float s  = __builtin_amdgcn_sinf(0.5f * t);
            const float cc = __builtin_amdgcn_cosf(0.5f * t);
            const float A  = t * t - t,  Ap = 2.f * t - 1.f;
            const float B  = x * x - x,  Bp = 2.f * x - 1.f;

            const float psi   = 2.f * x * s + A * B * D;
            const float psi_x = 2.f * s + A * (Bp * D + B * Dx);

            const float forcing = s * (2.f - PI_F * PI_F * x * x
                                       + 2.f * x * x * x * s);
            const float res = 4.f * PI_F * cc - 2.f * PI_F * PI_F * x * s
                            + 2.f * (A + B + Ap * Bp) * D
                            + 2.f * (A * Bp + Ap * B) * Dd
                            + A * B * Ddd
                            + psi * psi_x - forcing;
            float s4 = fabsf(res);
            s4 += __shfl_xor(s4, 1, 64);
            s4 += __shfl_xor(s4, 2, 64);
            s4 += __shfl_xor(s4, 4, 64);
            s4 += __shfl_xor(s4, 8, 64);
            if (tid == 0) bsum += s4;
        }
    }

    if (tid == 0) partial[blockIdx.x] = bsum;
}

__global__ __launch_bounds__(256) void pinn_prep(
    const float* __restrict__ W2, const float* __restrict__ W3,
    const float* __restrict__ Wo, half_t* __restrict__ wsH)
{
    const int tid = threadIdx.x;
    for (int idx = tid; idx < 4096; idx += 256) {
        const int n = idx >> 6, k = idx & 63;
        wsH[idx]        = (half_t)W2[k * 64 + n];   // Wt2[n][k]
        wsH[4096 + idx] = (half_t)W3[k * 64 + n];   // Wt3[n][k]
    }
    if (tid < 64) wsH[8192 + tid] = (half_t)Wo[tid];
}

__global__ __launch_bounds__(256) void pinn_reduce(
    const float* __restrict__ partial, float* __restrict__ out,
    int nblocks, float invN)
{
    __shared__ float sd[256];
    float s = 0.f;
    for (int i = threadIdx.x; i < nblocks; i += 256) s += partial[i];
    sd[threadIdx.x] = s;
    __syncthreads();
    #pragma unroll
    for (int off = 128; off > 0; off >>= 1) {
        if (threadIdx.x < off) sd[threadIdx.x] += sd[threadIdx.x + off];
        __syncthreads();
    }
    if (threadIdx.x == 0) out[0] = sd[0] * invN;
}

extern "C" void kernel_launch(void* const* d_in, const int* in_sizes, int n_in,
                              void* d_out, int out_size, void* d_ws, size_t ws_size,
                              hipStream_t stream)
{
    const float* pts = (const float*)d_in[0];
    const float* W1  = (const float*)d_in[1];
    const float* b1  = (const float*)d_in[2];
    const float* W2  = (const float*)d_in[3];
    const float* b2  = (const float*)d_in[4];
    const float* W3  = (const float*)d_in[5];
    const float* b3  = (const float*)d_in[6];
    const float* Wo  = (const float*)d_in[7];
    // d_in[8] = bo: cancels in (u - u(1,t)) and has zero derivative.

    const int nPts    = in_sizes[0] / 2;          // 262144
    const int nBlocks = nPts / 32;                // 8192 (32 pts = 2 passes x 16)

    half_t* wsH     = (half_t*)d_ws;                      // 16,512 B of weights
    float*  partial = (float*)((char*)d_ws + 32768);      // 32 KB of partials

    pinn_prep<<<1, 256, 0, stream>>>(W2, W3, Wo, wsH);
    pinn_main<<<nBlocks, 256, 0, stream>>>(pts, W1, b1, b2, b3, wsH, partial);
    pinn_reduce<<<1, 256, 0, stream>>>(partial, (float*)d_out, nBlocks,
                                       1.f / (float)nPts);
}

// Round 18
// 114.309 us; speedup vs baseline: 1.0754x; 1.0225x over previous
//
#include <hip/hip_runtime.h>
#include <math.h>

typedef _Float16 half_t;
typedef half_t half8 __attribute__((ext_vector_type(8)));
typedef __fp16 fp16x2 __attribute__((ext_vector_type(2)));   // cvt_pkrtz return type
typedef float f32x4 __attribute__((ext_vector_type(4)));
typedef float f32x2 __attribute__((ext_vector_type(2)));     // -> v_pk_*_f32

#define PI_F 3.14159265358979323846f

__device__ __forceinline__ f32x2 splat2(float s) { return f32x2{s, s}; }
__device__ __forceinline__ f32x2 fma2(f32x2 a, f32x2 b, f32x2 c) {
    return __builtin_elementwise_fma(a, b, c);
}

// Fast tanh (packed pair): tanh(z) = 1 - 2*rcp(e^{2z}+1), e^{2z} = 2^(z*2/ln2).
// 7 wave-ops/pair. No clamp (|z| < ~10 here; overflow needs |z| > 44).
__device__ __forceinline__ f32x2 ftanh2(f32x2 z) {
    const f32x2 m = z * splat2(2.8853900817779268f);   // 2/ln2
    f32x2 t;
    t[0] = exp2f(m[0]);          // v_exp_f32
    t[1] = exp2f(m[1]);
    const f32x2 s = t + splat2(1.f);
    f32x2 r;
    r[0] = __builtin_amdgcn_rcpf(s[0]);
    r[1] = __builtin_amdgcn_rcpf(s[1]);
    return fma2(splat2(-2.f), r, splat2(1.f));
}

// ===== R18 = R15 structure + phase-local register diet =====
//
// DIRECTIONAL-JET (R15): interior {v,x,d,dd}, d = dx+dt; boundary
// {v,x,t,xt,tt,xtt}; L3 combines boundary to 3. Residual (exact):
//   res = 4*pi*cos - 2*pi^2*x*s + 2(A+B+A'B')D + 2(AB'+A'B)Dd + AB*Ddd
//         + psi*psi_x - forcing.
//
// REGISTER DIET (R18): all phase-local constants (W-frags, biases, wo)
// are RELOADED inside their phase each pass, behind an opaque
// asm("":"+s"(ptr)) that defeats loop-invariant hoisting. Every reload is
// an L1-hit issued before the phase's entry barrier (latency hidden).
// Peak liveness drops from ~80 to ~acc(40)+frag(8)+bias(4)+addr ~= 64-66,
// targeting the 73-VGPR (7 waves/EU) or 64-VGPR (8 waves/EU) step.
//
// TRANSPOSED layout: J^T[n = c*16 + p][k = j], XOR-swizzled:
//   halfidx(n,k) = n*64 + (((k>>3) ^ (n&7)) << 3) + (k&7)
//
// LESSONS (do not revisit):
//  R4:  launch_bounds occupancy arg -> spill disaster.
//  R11: hoisting ADDS live regs -> lost a wave/EU, +21%. (R18 inverts this.)
//  R13: ping-pong dbuf -> LDS+VGPR blowup, +15%.
//  R16: fusing GEMV off MFMA onto VALU/shfl -> +5%. Fuse INTO idle pipes.
__global__ __launch_bounds__(256) void pinn_main(
    const float* __restrict__ pts,
    const float* __restrict__ W1, const float* __restrict__ b1,
    const float* __restrict__ b2, const float* __restrict__ b3,
    const half_t* __restrict__ wsH,    // Wt2 @0, Wt3 @4096, Wo @8192 (half idx)
    float* __restrict__ partial)
{
    __shared__ __align__(16) half_t J[160 * 64];   // 20 KB
    __shared__ float ubuf[7][16];                  // u[c][p] stage for residual

    const int tid = threadIdx.x;
    const int l   = tid & 63;
    const int w   = tid >> 6;       // wave = output-neuron M-tile (rows of Z^T)
    const int q   = l >> 4;
    const int i   = l & 15;         // = point p owned for compose/writes
    const int ja  = w * 16 + i;     // A-operand weight row
    const int jb  = w * 16 + q * 4; // first of 4 output-neuron cols owned

    // loop-invariant LDS bases (halves)
    const int rb0 = i * 64 + ((q ^ (i & 7)) << 3);          // B-frag, k-chunk q*8
    const int rb1 = i * 64 + (((4 + q) ^ (i & 7)) << 3);    // B-frag, k-chunk 32+q*8
    const int wbase = i * 64 + ((((w * 2 + (q >> 1)) ^ (i & 7))) << 3) + (q & 1) * 4;

    // packed write: one b64 = comp c for 4 neurons; pure bit-cast (no v-inserts)
    auto stc = [&](int c, f32x2 v01, f32x2 v23) {
        uint2 d;
        d.x = __builtin_bit_cast(unsigned int,
                                 __builtin_amdgcn_cvt_pkrtz(v01[0], v01[1]));
        d.y = __builtin_bit_cast(unsigned int,
                                 __builtin_amdgcn_cvt_pkrtz(v23[0], v23[1]));
        *(uint2*)(&J[wbase + c * 1024]) = d;
    };

    float bsum = 0.f;

    #pragma unroll 1
    for (int pass = 0; pass < 2; ++pass) {
        const int pbase = blockIdx.x * 32 + pass * 16;

        const float2 xy = *(const float2*)(pts + 2 * (pbase + i));   // point p = i
        const float X = xy.x, T = xy.y;

        // -------- layer 1 (2 -> 64): jets for point i, 4 neurons --------
        {
            // phase-local reload (opaque base defeats hoisting; L1-hit)
            const float* W1p = W1;
            const float* b1p = b1;
            asm volatile("" : "+s"(W1p), "+s"(b1p));
            const float4 w04 = *(const float4*)(W1p + jb);
            const float4 w14 = *(const float4*)(W1p + 64 + jb);
            const float4 b14 = *(const float4*)(b1p + jb);
            const f32x2 w0a = {w04.x, w04.y}, w0b = {w04.z, w04.w};
            const f32x2 w1a = {w14.x, w14.y}, w1b = {w14.z, w14.w};
            const f32x2 bba = {b14.x, b14.y}, bbb = {b14.z, b14.w};

            {   // interior jet at (x,t): {v, x, d, dd}; z_x=w0, z_d=w0+w1, z_dd=0
                const f32x2 wda = w0a + w1a, wdb = w0b + w1b;
                const f32x2 zva = fma2(splat2(X), w0a, fma2(splat2(T), w1a, bba));
                const f32x2 zvb = fma2(splat2(X), w0b, fma2(splat2(T), w1b, bbb));
                const f32x2 aa = ftanh2(zva), ab = ftanh2(zvb);
                const f32x2 d1a = splat2(1.f) - aa * aa, d1b = splat2(1.f) - ab * ab;
                const f32x2 d2a = splat2(-2.f) * aa * d1a, d2b = splat2(-2.f) * ab * d1b;
                stc(0, aa, ab);
                stc(1, d1a * w0a, d1b * w0b);
                stc(2, d1a * wda, d1b * wdb);
                stc(3, d2a * wda * wda, d2b * wdb * wdb);
            }
            {   // boundary jet at (1,t): {v, x, t, xt, tt, xtt} (comps 4..9)
                const f32x2 zva = fma2(splat2(T), w1a, bba + w0a);
                const f32x2 zvb = fma2(splat2(T), w1b, bbb + w0b);
                const f32x2 aa = ftanh2(zva), ab = ftanh2(zvb);
                const f32x2 e1a = splat2(1.f) - aa * aa, e1b = splat2(1.f) - ab * ab;
                const f32x2 e2a = splat2(-2.f) * aa * e1a, e2b = splat2(-2.f) * ab * e1b;
                const f32x2 e3a = splat2(-2.f) * (e1a * e1a + aa * e2a);
                const f32x2 e3b = splat2(-2.f) * (e1b * e1b + ab * e2b);
                stc(4, aa, ab);
                stc(5, e1a * w0a, e1b * w0b);
                stc(6, e1a * w1a, e1b * w1b);
                stc(7, e2a * w0a * w1a, e2b * w0b * w1b);
                stc(8, e2a * w1a * w1a, e2b * w1b * w1b);
                stc(9, e3a * w0a * w1a * w1a, e3b * w0b * w1b * w1b);
            }
        }

        // -------- hidden layer: MFMA jet-GEMM + packed compose --------
        // W-frags + bias reloaded per call behind opaque bases (phase-local).
        auto layer_step = [&](int woff, const float* bp, bool combine) {
            const half_t* wp = wsH;
            const float* bpp = bp;
            asm volatile("" : "+s"(wp), "+s"(bpp));
            const half8 A0 = *(const half8*)(wp + woff + ja * 64 + q * 8);
            const half8 A1 = *(const half8*)(wp + woff + ja * 64 + 32 + q * 8);
            const float4 b4 = *(const float4*)(bpp + jb);

            __syncthreads();   // J ready
            const f32x4 zb = {b4.x, b4.y, b4.z, b4.w};
            const f32x4 z0 = {0.f, 0.f, 0.f, 0.f};
            f32x4 acc[10];
            #pragma unroll
            for (int c = 0; c < 10; ++c) {
                const half8 f0 = *(const half8*)(&J[rb0 + c * 1024]);
                const half8 f1 = *(const half8*)(&J[rb1 + c * 1024]);
                f32x4 z = (c == 0 || c == 4) ? zb : z0;   // bias into C-init (v comps)
                z = __builtin_amdgcn_mfma_f32_16x16x32_f16(A0, f0, z, 0, 0, 0);
                z = __builtin_amdgcn_mfma_f32_16x16x32_f16(A1, f1, z, 0, 0, 0);
                acc[c] = z;
            }
            __syncthreads();   // all reads of J done

            {   // interior jet {v, x, d, dd}, neuron pairs (01),(23)
                const f32x2 zva = {acc[0][0], acc[0][1]}, zvb = {acc[0][2], acc[0][3]};
                const f32x2 aa = ftanh2(zva), ab = ftanh2(zvb);
                const f32x2 d1a = splat2(1.f) - aa * aa, d1b = splat2(1.f) - ab * ab;
                const f32x2 d2a = splat2(-2.f) * aa * d1a, d2b = splat2(-2.f) * ab * d1b;
                const f32x2 zxa = {acc[1][0], acc[1][1]}, zxb = {acc[1][2], acc[1][3]};
                const f32x2 zda = {acc[2][0], acc[2][1]}, zdb = {acc[2][2], acc[2][3]};
                const f32x2 zdda = {acc[3][0], acc[3][1]}, zddb = {acc[3][2], acc[3][3]};
                stc(0, aa, ab);
                stc(1, d1a * zxa, d1b * zxb);
                stc(2, d1a * zda, d1b * zdb);
                stc(3, fma2(d2a * zda, zda, d1a * zdda),
                       fma2(d2b * zdb, zdb, d1b * zddb));
            }
            {   // boundary jet (comps 4..9)
                const f32x2 zva = {acc[4][0], acc[4][1]}, zvb = {acc[4][2], acc[4][3]};
                const f32x2 aa = ftanh2(zva), ab = ftanh2(zvb);
                const f32x2 e1a = splat2(1.f) - aa * aa, e1b = splat2(1.f) - ab * ab;
                const f32x2 e2a = splat2(-2.f) * aa * e1a, e2b = splat2(-2.f) * ab * e1b;
                const f32x2 e3a = splat2(-2.f) * (e1a * e1a + aa * e2a);
                const f32x2 e3b = splat2(-2.f) * (e1b * e1b + ab * e2b);
                const f32x2 zxa  = {acc[5][0], acc[5][1]},  zxb  = {acc[5][2], acc[5][3]};
                const f32x2 zta  = {acc[6][0], acc[6][1]},  ztb  = {acc[6][2], acc[6][3]};
                const f32x2 zxta = {acc[7][0], acc[7][1]},  zxtb = {acc[7][2], acc[7][3]};
                const f32x2 ztta = {acc[8][0], acc[8][1]},  zttb = {acc[8][2], acc[8][3]};
                const f32x2 zxtta = {acc[9][0], acc[9][1]}, zxttb = {acc[9][2], acc[9][3]};
                if (combine) {   // residual uses only (v+x), (t+xt), (tt+xtt) — exact
                    stc(4, aa + e1a * zxa, ab + e1b * zxb);
                    stc(5, fma2(e2a * zxa, zta, fma2(e1a, zxta, e1a * zta)),
                           fma2(e2b * zxb, ztb, fma2(e1b, zxtb, e1b * ztb)));
                    stc(6, fma2(e2a * zta, zta,
                                fma2(e1a, ztta,
                                     fma2(e3a * zxa, zta * zta,
                                          fma2(e2a, fma2(splat2(2.f) * zxta, zta,
                                                         zxa * ztta),
                                               e1a * zxtta)))),
                           fma2(e2b * ztb, ztb,
                                fma2(e1b, zttb,
                                     fma2(e3b * zxb, ztb * ztb,
                                          fma2(e2b, fma2(splat2(2.f) * zxtb, ztb,
                                                         zxb * zttb),
                                               e1b * zxttb)))));
                } else {
                    stc(4, aa, ab);
                    stc(5, e1a * zxa, e1b * zxb);
                    stc(6, e1a * zta, e1b * ztb);
                    stc(7, fma2(e2a * zxa, zta, e1a * zxta),
                           fma2(e2b * zxb, ztb, e1b * zxtb));
                    stc(8, fma2(e2a * zta, zta, e1a * ztta),
                            fma2(e2b * ztb, ztb, e1b * zttb));
                    stc(9,
                        fma2(e3a * zxa, zta * zta,
                             fma2(e2a, fma2(splat2(2.f) * zxta, zta, zxa * ztta),
                                  e1a * zxtta)),
                        fma2(e3b * zxb, ztb * ztb,
                             fma2(e2b, fma2(splat2(2.f) * zxtb, ztb, zxb * zttb),
                                  e1b * zxttb)));
                }
            }
        };
        layer_step(0, b2, false);
        layer_step(4096, b3, true);    // 7-comp J3
        __syncthreads();   // J3 ready

        // ---- output GEMV (Wo as A row 0): 7 tiles, wave w owns c = 2w, 2w+1 ----
        {
            const half_t* wop = wsH;
            asm volatile("" : "+s"(wop));
            half8 wo0 = {0, 0, 0, 0, 0, 0, 0, 0};
            half8 wo1 = {0, 0, 0, 0, 0, 0, 0, 0};
            if (i == 0) {
                wo0 = *(const half8*)(wop + 8192 + q * 8);
                wo1 = *(const half8*)(wop + 8192 + 32 + q * 8);
            }
            #pragma unroll
            for (int k3 = 0; k3 < 2; ++k3) {
                const int c = w * 2 + k3;
                if (c < 7) {
                    const half8 f0 = *(const half8*)(&J[rb0 + c * 1024]);
                    const half8 f1 = *(const half8*)(&J[rb1 + c * 1024]);
                    f32x4 z = {0.f, 0.f, 0.f, 0.f};
                    z = __builtin_amdgcn_mfma_f32_16x16x32_f16(wo0, f0, z, 0, 0, 0);
                    z = __builtin_amdgcn_mfma_f32_16x16x32_f16(wo1, f1, z, 0, 0, 0);
                    if (q == 0) ubuf[c][i] = z[0];   // D row 0 -> q==0 lanes, reg 0
                }
            }
        }
        __syncthreads();   // ubuf ready; all J reads done (next L1 may write J)

        // ---------------- residual: one lane per point ----------------
        if (tid < 16) {
            // for tid<16: w=0,q=0,i=tid -> X,T are this point's coords
            const float x = X, t = T;
            float U[7];
            #pragma unroll
            for (int c = 0; c < 7; ++c) U[c] = ubuf[c][tid];

            const float D   = U[0] - U[4];     // u - (uB + uBx)
            const float Dx  = U[1];
            const float Dd  = U[2] - U[5];     // u_d - (uBt + uBxt)
            const float Ddd = U[3] - U[6];     // u_dd - (uBtt + uBxtt)

            // sin(pi t) = v_sin(t/2) [revolutions], t in [0,1]
            const float s  = __builtin_amdgcn_sinf(0.5f * t);
            const float cc = __builtin_amdgcn_cosf(0.5f * t);
            const float A  = t * t - t,  Ap = 2.f * t - 1.f;
            const float B  = x * x - x,  Bp = 2.f * x - 1.f;

            const float psi   = 2.f * x * s + A * B * D;
            const float psi_x = 2.f * s + A * (Bp * D + B * Dx);

            const float forcing = s * (2.f - PI_F * PI_F * x * x
                                       + 2.f * x * x * x * s);
            const float res = 4.f * PI_F * cc - 2.f * PI_F * PI_F * x * s
                            + 2.f * (A + B + Ap * Bp) * D
                            + 2.f * (A * Bp + Ap * B) * Dd
                            + A * B * Ddd
                            + psi * psi_x - forcing;
            float s4 = fabsf(res);
            s4 += __shfl_xor(s4, 1, 64);
            s4 += __shfl_xor(s4, 2, 64);
            s4 += __shfl_xor(s4, 4, 64);
            s4 += __shfl_xor(s4, 8, 64);
            if (tid == 0) bsum += s4;
        }
    }

    if (tid == 0) partial[blockIdx.x] = bsum;
}

__global__ __launch_bounds__(256) void pinn_prep(
    const float* __restrict__ W2, const float* __restrict__ W3,
    const float* __restrict__ Wo, half_t* __restrict__ wsH)
{
    const int tid = threadIdx.x;
    for (int idx = tid; idx < 4096; idx += 256) {
        const int n = idx >> 6, k = idx & 63;
        wsH[idx]        = (half_t)W2[k * 64 + n];   // Wt2[n][k]
        wsH[4096 + idx] = (half_t)W3[k * 64 + n];   // Wt3[n][k]
    }
    if (tid < 64) wsH[8192 + tid] = (half_t)Wo[tid];
}

__global__ __launch_bounds__(256) void pinn_reduce(
    const float* __restrict__ partial, float* __restrict__ out,
    int nblocks, float invN)
{
    __shared__ float sd[256];
    float s = 0.f;
    for (int i = threadIdx.x; i < nblocks; i += 256) s += partial[i];
    sd[threadIdx.x] = s;
    __syncthreads();
    #pragma unroll
    for (int off = 128; off > 0; off >>= 1) {
        if (threadIdx.x < off) sd[threadIdx.x] += sd[threadIdx.x + off];
        __syncthreads();
    }
    if (threadIdx.x == 0) out[0] = sd[0] * invN;
}

extern "C" void kernel_launch(void* const* d_in, const int* in_sizes, int n_in,
                              void* d_out, int out_size, void* d_ws, size_t ws_size,
                              hipStream_t stream)
{
    const float* pts = (const float*)d_in[0];
    const float* W1  = (const float*)d_in[1];
    const float* b1  = (const float*)d_in[2];
    const float* W2  = (const float*)d_in[3];
    const float* b2  = (const float*)d_in[4];
    const float* W3  = (const float*)d_in[5];
    const float* b3  = (const float*)d_in[6];
    const float* Wo  = (const float*)d_in[7];
    // d_in[8] = bo: cancels in (u - u(1,t)) and has zero derivative.

    const int nPts    = in_sizes[0] / 2;          // 262144
    const int nBlocks = nPts / 32;                // 8192 (32 pts = 2 passes x 16)

    half_t* wsH     = (half_t*)d_ws;                      // 16,512 B of weights
    float*  partial = (float*)((char*)d_ws + 32768);      // 32 KB of partials

    pinn_prep<<<1, 256, 0, stream>>>(W2, W3, Wo, wsH);
    pinn_main<<<nBlocks, 256, 0, stream>>>(pts, W1, b1, b2, b3, wsH, partial);
    pinn_reduce<<<1, 256, 0, stream>>>(partial, (float*)d_out, nBlocks,
                                       1.f / (float)nPts);
}